// Round 8
// baseline (159.374 us; speedup 1.0000x reference)
//
#include <hip/hip_runtime.h>
#include <hip/hip_bf16.h>

#define NN 512
#define DD 64
#define TOPK 20
#define BB 128

// =============== KPRE: norms (f64, bit-identical order), es, gstats zero =======
__global__ __launch_bounds__(256) void kpre(const float* __restrict__ emb,
                                            const float* __restrict__ attn_w,
                                            double* __restrict__ nrm,
                                            float* __restrict__ es_src,
                                            float* __restrict__ es_dst,
                                            double* __restrict__ gstats) {
    const int bid = blockIdx.x, t = threadIdx.x;
    if (bid < 2) {
        // f64 sumsq, c ascending, x,y,z,w -> bit-identical to R7's dj/di
        const int j = bid * 256 + t;
        const float4* e4 = (const float4*)emb;
        double s = 0.0;
        #pragma unroll
        for (int c = 0; c < 16; ++c) {
            const float4 v = e4[j * 16 + c];
            const double vx = v.x, vy = v.y, vz = v.z, vw = v.w;
            s += vx * vx; s += vy * vy; s += vz * vz; s += vw * vw;
        }
        nrm[j] = sqrt(s);
        if (bid == 0 && t < 128) gstats[t] = 0.0;
    } else {
        const int j = (bid - 2) * 256 + t;
        float s1 = 0.f, s2 = 0.f;
        #pragma unroll
        for (int c = 0; c < 64; ++c) {
            const float w = emb[j * 64 + c];
            s1 += w * attn_w[64 + c];
            s2 += w * attn_w[192 + c];
        }
        es_src[j] = s1;
        es_dst[j] = s2;
    }
}

// =============== L1: merged kernel =============================================
// blocks 0..127   : k1 topk, dot-only (norms precomputed). f64 dot accumulation
//                   order and selection tie-break bit-identical to round-7
//                   (passed) -> identical topk.
// blocks 128..639 : k2 GEMM (byte-identical to round 7).
__global__ __launch_bounds__(256) void L1_fused(const float* __restrict__ data,
                                                const float* __restrict__ emb,
                                                const float* __restrict__ fc_w,
                                                const float* __restrict__ fc_b,
                                                const float* __restrict__ attn_w,
                                                const double* __restrict__ nrmArr,
                                                float* __restrict__ z,
                                                float* __restrict__ zsrc,
                                                float* __restrict__ zdst,
                                                int* __restrict__ topk) {
    __shared__ __align__(16) char smem[36864];
    const int bid = blockIdx.x, t = threadIdx.x;
    const int wid = t >> 6, lane = t & 63;

    if (bid < 128) {
        // ---------------- k1: cos topk (dot-only) ----------------
        float4* lds4 = (float4*)smem;              // [128 rows][17] padded tile
        float4* wis4 = (float4*)(smem + 34816);    // [4 nodes][16] query rows
        const int i = bid * 4 + wid;
        const float4* e4 = (const float4*)emb;

        if (t < 64) wis4[t] = e4[(bid * 4 + (t >> 4)) * 16 + (t & 15)];
        __syncthreads();

        const double nrm_i = nrmArr[i];

        double v[8];
        for (int tile = 0; tile < 4; ++tile) {
            __syncthreads();
            for (int m = t; m < 2048; m += 256) {
                const int row = m >> 4, c = m & 15;
                lds4[row * 17 + c] = e4[tile * 2048 + m];   // coalesced global read
            }
            __syncthreads();
            #pragma unroll
            for (int rb = 0; rb < 2; ++rb) {
                const int slot = tile * 2 + rb;
                const int rl = rb * 64 + lane;
                double dot = 0.0;
                #pragma unroll
                for (int c = 0; c < 16; ++c) {
                    const float4 vv = lds4[rl * 17 + c];
                    const float4 w  = wis4[wid * 16 + c];   // same-addr broadcast
                    dot += (double)w.x * (double)vv.x;
                    dot += (double)w.y * (double)vv.y;
                    dot += (double)w.z * (double)vv.z;
                    dot += (double)w.w * (double)vv.w;
                }
                v[slot] = dot / (nrm_i * nrmArr[slot * 64 + lane]);
            }
        }

        for (int k = 0; k < TOPK; ++k) {
            double bv = v[0]; int bs = 0;
            #pragma unroll
            for (int s = 1; s < 8; ++s) if (v[s] > bv) { bv = v[s]; bs = s; }
            int bi = bs * 64 + lane;
            #pragma unroll
            for (int off = 32; off > 0; off >>= 1) {
                double ov = __shfl_xor(bv, off);
                int    oi = __shfl_xor(bi, off);
                if (ov > bv || (ov == bv && oi < bi)) { bv = ov; bi = oi; }
            }
            if (lane == 0) topk[i * TOPK + k] = bi;
            if ((bi & 63) == lane) v[bi >> 6] = -1e300;
        }
    } else {
        // ---------------- k2: GEMM, 4 waves x 32 rows/block (unchanged) --------
        float* WsT = (float*)smem;               // [64 f][65] : WsT[f][d]=fc_w[d][f]
        const float4* fcw4 = (const float4*)fc_w;
        for (int m = t; m < 1024; m += 256) {
            const int d = m >> 4, f4 = m & 15;
            float4 v = fcw4[d * 16 + f4];
            WsT[(f4 * 4 + 0) * 65 + d] = v.x;
            WsT[(f4 * 4 + 1) * 65 + d] = v.y;
            WsT[(f4 * 4 + 2) * 65 + d] = v.z;
            WsT[(f4 * 4 + 3) * 65 + d] = v.w;
        }
        __syncthreads();

        float Breg[64];
        #pragma unroll
        for (int f = 0; f < 64; ++f) Breg[f] = WsT[f * 65 + lane];  // coalesced LDS

        const float bias = fc_b[lane];
        const float aw0  = attn_w[lane];
        const float aw2  = attn_w[128 + lane];
        const long rbase = ((long)(bid - 128) * 4 + wid) * 32;

        #pragma unroll
        for (int g = 0; g < 4; ++g) {
            float a8[8];
            #pragma unroll
            for (int r = 0; r < 8; ++r)
                a8[r] = data[(rbase + g * 8 + r) * 64 + lane];   // coalesced
            #pragma unroll
            for (int r = 0; r < 8; ++r) {
                float acc = 0.f;
                #pragma unroll
                for (int f = 0; f < 64; ++f) {
                    const float af = __int_as_float(
                        __builtin_amdgcn_readlane(__float_as_int(a8[r]), f));
                    acc = fmaf(af, Breg[f], acc);
                }
                const float zb = acc + bias;
                const long row = rbase + g * 8 + r;
                z[row * 64 + lane] = zb;
                float p1 = zb * aw0, p2 = zb * aw2;
                #pragma unroll
                for (int off = 32; off > 0; off >>= 1) {
                    p1 += __shfl_xor(p1, off);
                    p2 += __shfl_xor(p2, off);
                }
                if (lane == 0) { zsrc[row] = p1; zdst[row] = p2; }
            }
        }
    }
}

// =============== K3: LDS-staged gather + one-shot softmax + BN atomics =========
__global__ __launch_bounds__(256) void k3_attn(const float* __restrict__ z,
                                               const float* __restrict__ zsrc,
                                               const float* __restrict__ zdst,
                                               const float* __restrict__ es_src,
                                               const float* __restrict__ es_dst,
                                               const int* __restrict__ topk,
                                               const float* __restrict__ emb,
                                               const float* __restrict__ attn_b_p,
                                               float* __restrict__ rst,
                                               double* __restrict__ gstats) {
    __shared__ float  zs[512 * 16];          // 32 KB
    __shared__ double alf_pool[2560];        // 20 KB: alpha[256][20] / BN-reduce alias
    __shared__ unsigned short sIdx[256 * 20];// 10 KB
    float* alf = (float*)alf_pool;

    const int b    = blockIdx.x >> 2;
    const int dq   = blockIdx.x & 3;
    const int doff = dq * 16;
    const int t    = threadIdx.x;
    const float attn_b = *attn_b_p;
    const long b512 = (long)b * NN;

    float4* zs4 = (float4*)zs;
    for (int m = t; m < 2048; m += 256) {
        const int n = m >> 2, c4i = m & 3;
        zs4[m] = *(const float4*)(z + (b512 + n) * 64 + doff + c4i * 4);
    }
    __syncthreads();

    const int c4 = t & 3;
    const int rq = t >> 2;
    double s1[4] = {0,0,0,0}, s2[4] = {0,0,0,0};

    for (int chunk = 0; chunk < 2; ++chunk) {
        {
            const int n = chunk * 256 + t;
            const float sd = zdst[b512 + n] + es_dst[n] + attn_b;
            float ev[TOPK];
            float m0 = -1e30f;
            #pragma unroll
            for (int tt = 0; tt < TOPK; ++tt) {
                const int s = topk[n + tt * NN];   // scrambled flat edge list
                sIdx[t * TOPK + tt] = (unsigned short)s;
                float e = zsrc[b512 + s] + es_src[s] + sd;
                e = (e >= 0.f) ? e : 0.2f * e;
                ev[tt] = e;
                m0 = fmaxf(m0, e);
            }
            float dsum = 0.f;
            #pragma unroll
            for (int tt = 0; tt < TOPK; ++tt) { ev[tt] = __expf(ev[tt] - m0); dsum += ev[tt]; }
            const float inv = 1.0f / dsum;
            #pragma unroll
            for (int tt = 0; tt < TOPK; ++tt) alf[t * TOPK + tt] = ev[tt] * inv;
        }
        __syncthreads();

        #pragma unroll
        for (int it = 0; it < 4; ++it) {
            const int nl = it * 64 + rq;
            const int n  = chunk * 256 + nl;
            float4 acc = {0.f, 0.f, 0.f, 0.f};
            #pragma unroll
            for (int tt = 0; tt < TOPK; ++tt) {
                const float a = alf[nl * TOPK + tt];
                const float4 zv = zs4[(int)sIdx[nl * TOPK + tt] * 4 + c4];
                acc.x += a * zv.x; acc.y += a * zv.y; acc.z += a * zv.z; acc.w += a * zv.w;
            }
            const float4 ev = *(const float4*)&emb[n * 64 + doff + c4 * 4];
            float4 r;
            r.x = acc.x * ev.x; r.y = acc.y * ev.y; r.z = acc.z * ev.z; r.w = acc.w * ev.w;
            *(float4*)&rst[(b512 + n) * 64 + doff + c4 * 4] = r;
            s1[0] += (double)r.x; s2[0] += (double)r.x * (double)r.x;
            s1[1] += (double)r.y; s2[1] += (double)r.y * (double)r.y;
            s1[2] += (double)r.z; s2[2] += (double)r.z * (double)r.z;
            s1[3] += (double)r.w; s2[3] += (double)r.w * (double)r.w;
        }
        __syncthreads();
    }

    double* r1 = alf_pool;
    double* r2 = alf_pool + 1024;
    #pragma unroll
    for (int j = 0; j < 4; ++j) {
        r1[(c4 * 4 + j) * 64 + rq] = s1[j];
        r2[(c4 * 4 + j) * 64 + rq] = s2[j];
    }
    __syncthreads();
    if (t < 16) {
        double a = 0.0, bb = 0.0;
        for (int q = 0; q < 64; ++q) { a += r1[t * 64 + q]; bb += r2[t * 64 + q]; }
        atomicAdd(&gstats[doff + t], a);
        atomicAdd(&gstats[64 + doff + t], bb);
    }
}

// =============== K5: BN finalize (per-block) + apply + ReLU + out_w dot ========
__global__ __launch_bounds__(256) void k5_out(const float* __restrict__ rst,
                                              const double* __restrict__ gstats,
                                              const float* __restrict__ gamma,
                                              const float* __restrict__ beta,
                                              const float* __restrict__ out_w,
                                              const float* __restrict__ out_b_p,
                                              float* __restrict__ out) {
    __shared__ float scv[64], biv[64];
    const int t = threadIdx.x;
    if (t < 64) {
        const double M = (double)BB * (double)NN;
        const double s  = gstats[t];
        const double s2 = gstats[64 + t];
        const double mu  = s / M;
        const double var = s2 / M - mu * mu;
        const float scale = (float)((double)gamma[t] / sqrt(var + 1e-5));
        scv[t] = scale;
        biv[t] = beta[t] - (float)mu * scale;
    }
    __syncthreads();

    const int wid = t >> 6, lane = t & 63;
    const float sc = scv[lane], bi = biv[lane], ow = out_w[lane];
    const float ob = *out_b_p;
    const long rowbase = (long)blockIdx.x * 16 + wid * 4;
    float v[4];
    #pragma unroll
    for (int rr = 0; rr < 4; ++rr)
        v[rr] = fmaxf(rst[(rowbase + rr) * 64 + lane] * sc + bi, 0.f) * ow;
    #pragma unroll
    for (int off = 32; off > 0; off >>= 1)
        #pragma unroll
        for (int rr = 0; rr < 4; ++rr) v[rr] += __shfl_down(v[rr], off);
    if (lane == 0)
        #pragma unroll
        for (int rr = 0; rr < 4; ++rr) out[rowbase + rr] = v[rr] + ob;
}

extern "C" void kernel_launch(void* const* d_in, const int* in_sizes, int n_in,
                              void* d_out, int out_size, void* d_ws, size_t ws_size,
                              hipStream_t stream) {
    const float* data   = (const float*)d_in[0];
    const float* emb    = (const float*)d_in[1];
    const float* fc_w   = (const float*)d_in[2];
    const float* fc_b   = (const float*)d_in[3];
    const float* attn_w = (const float*)d_in[4];
    const float* attn_b = (const float*)d_in[5];
    const float* gamma  = (const float*)d_in[6];
    const float* beta   = (const float*)d_in[7];
    const float* out_w  = (const float*)d_in[8];
    const float* out_b  = (const float*)d_in[9];
    float* out = (float*)d_out;

    char* ws = (char*)d_ws;
    float*  z      = (float*) (ws + 0);            // 16 MB
    float*  rst    = (float*) (ws + 16777216);     // 16 MB
    float*  zsrc   = (float*) (ws + 33554432);     // 256 KB
    float*  zdst   = (float*) (ws + 33816576);     // 256 KB
    int*    topk   = (int*)   (ws + 34078720);     // 40 KB
    float*  es_src = (float*) (ws + 34119680);     // 2 KB
    float*  es_dst = (float*) (ws + 34121728);     // 2 KB
    double* gstats = (double*)(ws + 34123776);     // 1 KB
    double* nrm    = (double*)(ws + 34124800);     // 4 KB

    kpre<<<4, 256, 0, stream>>>(emb, attn_w, nrm, es_src, es_dst, gstats);
    L1_fused<<<640, 256, 0, stream>>>(data, emb, fc_w, fc_b, attn_w, nrm,
                                      z, zsrc, zdst, topk);
    k3_attn<<<BB * 4, 256, 0, stream>>>(z, zsrc, zdst, es_src, es_dst, topk, emb,
                                        attn_b, rst, gstats);
    k5_out<<<4096, 256, 0, stream>>>(rst, gstats, gamma, beta, out_w, out_b, out);
}